// Round 14
// baseline (3395.388 us; speedup 1.0000x reference)
//
#include <hip/hip_runtime.h>
#include <hip/hip_fp16.h>

// Sizes fixed by the problem.
#define B_   64
#define T_   1024
#define H1_  128
#define H2_  256
#define TC_  128              // time-chunk for LSTM3/4 and LSTM1/2
#define NCH  (T_ / TC_)       // 8 chunks
#define MCH  (B_ * TC_)       // 8192 rows per chunk per layer

typedef unsigned int  u32;
typedef unsigned short u16;
typedef _Float16 half2_t __attribute__((ext_vector_type(2)));
typedef _Float16 half8 __attribute__((ext_vector_type(8)));
typedef float f32x4 __attribute__((ext_vector_type(4)));

__device__ __forceinline__ float fdot2(u32 w, u32 h, float acc) {
    return __builtin_amdgcn_fdot2(__builtin_bit_cast(half2_t, w),
                                  __builtin_bit_cast(half2_t, h), acc, false);
}
__device__ __forceinline__ u32 pk2(float a, float b) {
    __half2 h = __floats2half2_rn(a, b);
    return __builtin_bit_cast(u32, h);
}
__device__ __forceinline__ float hf(u16 u) { return __half2float(__builtin_bit_cast(__half, u)); }
__device__ __forceinline__ u16 fh(float f) { return __builtin_bit_cast(u16, __float2half(f)); }
__device__ __forceinline__ float sigf(float x) { return 1.0f / (1.0f + expf(-x)); }

// ---------------------------------------------------------------------------
// Weight conversions (packed fp16 pairs) + small-LSTM prologue precompute.
// (unchanged from r13)
// ---------------------------------------------------------------------------
__global__ void cvt_all(const float* __restrict__ Wh3, const float* __restrict__ Wh4,
                        const float* __restrict__ Wi3, const float* __restrict__ Wi4,
                        const float* __restrict__ attW,
                        const float* __restrict__ Wh1, const float* __restrict__ Wh2,
                        const float* __restrict__ cw, const float* __restrict__ cb,
                        const float* __restrict__ Wi1, const float* __restrict__ Wi2,
                        const float* __restrict__ b1, const float* __restrict__ b2,
                        u32* __restrict__ wpk, u32* __restrict__ wi3T,
                        u32* __restrict__ wi4T, u32* __restrict__ awT,
                        uint4* __restrict__ wpkT, u32* __restrict__ whs,
                        float* __restrict__ w4s, float* __restrict__ beffs)
{
    int idx = blockIdx.x * 256 + threadIdx.x;   // < 652288
    if (idx < 262144) {
        int l = idx >> 17, rem = idx & 131071, k2 = rem >> 10, j = rem & 1023;
        const float* W = l ? Wh4 : Wh3;
        wpk[idx] = pk2(W[(2 * k2) * 1024 + j], W[(2 * k2 + 1) * 1024 + j]);
    } else if (idx < 393216) {
        int rel = idx - 262144, n = rel >> 7, kp = rel & 127;   // [n][kp]
        wi3T[rel] = pk2(Wi3[(2 * kp) * 1024 + n], Wi3[(2 * kp + 1) * 1024 + n]);
    } else if (idx < 524288) {
        int rel = idx - 393216, n = rel >> 7, kp = rel & 127;   // [n][kp], flip
        wi4T[rel] = pk2(Wi4[(255 - 2 * kp) * 1024 + n], Wi4[(254 - 2 * kp) * 1024 + n]);
    } else if (idx < 557056) {
        int rel = idx - 524288, n = rel >> 8, kp = rel & 255;   // [n][kp]
        awT[rel] = pk2(attW[(2 * kp) * 128 + n], attW[(2 * kp + 1) * 128 + n]);
    } else if (idx < 585728) {
        int rel = idx - 557056;          // < 28672 = 2 * 14 * 1024
        int l = rel / 14336;
        int rem = rel - l * 14336;
        int q = rem >> 10, col = rem & 1023;
        const float* W = l ? Wh4 : Wh3;
        int k2 = 72 + 4 * q;
        uint4 v;
        v.x = pk2(W[(2 * k2 + 0) * 1024 + col], W[(2 * k2 + 1) * 1024 + col]);
        v.y = pk2(W[(2 * k2 + 2) * 1024 + col], W[(2 * k2 + 3) * 1024 + col]);
        v.z = pk2(W[(2 * k2 + 4) * 1024 + col], W[(2 * k2 + 5) * 1024 + col]);
        v.w = pk2(W[(2 * k2 + 6) * 1024 + col], W[(2 * k2 + 7) * 1024 + col]);
        wpkT[rel] = v;
    } else if (idx < 651264) {
        int rel = idx - 585728;          // < 65536 = 2 * 64 * 512
        int l = rel >> 15, rem = rel & 32767, p = rem >> 9, col = rem & 511;
        const float* W = l ? Wh2 : Wh1;
        whs[rel] = pk2(W[(2 * p) * 512 + col], W[(2 * p + 1) * 512 + col]);
    } else if (idx < 652288) {
        int rel = idx - 651264;          // < 1024
        int l = rel >> 9, col = rel & 511;
        const float* Wi = l ? Wi2 : Wi1;
        const float* bb = l ? b2 : b1;
#pragma unroll
        for (int kk = 0; kk < 4; ++kk) {
            float s = 0.f;
#pragma unroll
            for (int c0 = 0; c0 < 16; ++c0) {
                int cc = l ? (15 - c0) : c0;
                s += cw[kk * 16 + c0] * Wi[cc * 512 + col];
            }
            w4s[(l * 4 + kk) * 512 + col] = s;
        }
        float be = bb[col];
#pragma unroll
        for (int c0 = 0; c0 < 16; ++c0) {
            int cc = l ? (15 - c0) : c0;
            be += cb[c0] * Wi[cc * 512 + col];
        }
        beffs[l * 512 + col] = be;
    }
}

// ---------------------------------------------------------------------------
// FUSED persistent step: 256 blocks, 512 threads.
//  blocks   0..127: LSTM3/4 (big) chunk c-1  (skipped when c == 0)
//  blocks 128..255: LSTM1/2 (small) chunk c  (skipped when c == NCH)
// r14 change (big only): the 56 per-step-streamed weight pairs (229 KB/CU/step,
// the r12/r13 bottleneck) now live in 112 AGPRs per thread via inline-asm
// v_accvgpr_write/read. gfx950's unified 512-reg file supports VGPR(≈128) +
// AGPR(112) at the LDS-pinned occupancy (1 block/CU, 2 waves/SIMD, ≤256 regs).
// asm volatile on the reads pins them in-loop (hoisting would spill 112 VGPRs).
// ---------------------------------------------------------------------------
__global__ __launch_bounds__(512) void fused_step(
    const u16* __restrict__ pre, const u32* __restrict__ wpk,
    const uint4* __restrict__ wpkT, float* __restrict__ state,
    u16* __restrict__ enc,
    const float* __restrict__ X, const u32* __restrict__ whs,
    const float* __restrict__ w4s, const float* __restrict__ beffs,
    float* __restrict__ sstC, u16* __restrict__ sstH,
    u16* __restrict__ x12, int c)
{
    __shared__ __align__(16) uint4 wlA[9][512];
    __shared__ __align__(16) uint4 wlB[9][512];
    __shared__ __align__(16) u32 hbuf_pk[128];
    __shared__ float zbuf[1024];
    __shared__ __align__(16) u32 hbs[64];

    const int j = threadIdx.x;

    if (blockIdx.x < 128) {
        // ----------------------------- BIG ---------------------------------
        if (c == 0) return;
        const int t0 = (c - 1) * TC_;
        const int blk = blockIdx.x;
        const int b = blk >> 1;
        const int layer = blk & 1;

        const u32* wp = wpk + (size_t)layer * 131072;
        u32 wrA[36], wrB[36];
#pragma unroll
        for (int q = 0; q < 36; ++q) {
            wrA[q] = wp[q * 1024 + j];
            wrB[q] = wp[q * 1024 + 512 + j];
        }
#pragma unroll
        for (int m = 0; m < 9; ++m) {
            uint4 va, vb;
            va.x = wp[(36 + 4 * m + 0) * 1024 + j];
            va.y = wp[(36 + 4 * m + 1) * 1024 + j];
            va.z = wp[(36 + 4 * m + 2) * 1024 + j];
            va.w = wp[(36 + 4 * m + 3) * 1024 + j];
            vb.x = wp[(36 + 4 * m + 0) * 1024 + 512 + j];
            vb.y = wp[(36 + 4 * m + 1) * 1024 + 512 + j];
            vb.z = wp[(36 + 4 * m + 2) * 1024 + 512 + j];
            vb.w = wp[(36 + 4 * m + 3) * 1024 + 512 + j];
            wlA[m][j] = va;
            wlB[m][j] = vb;
        }
        // pairs 72..127 (formerly streamed every step): park in 112 AGPRs.
        const uint4* wt = wpkT + (size_t)layer * 14 * 1024;
        u32 ag[112];
#pragma unroll
        for (int q = 0; q < 14; ++q) {
            uint4 wa = wt[q * 1024 + j];
            uint4 wb = wt[q * 1024 + 512 + j];
            asm volatile("v_accvgpr_write_b32 %0, %1" : "=a"(ag[q * 8 + 0]) : "v"(wa.x));
            asm volatile("v_accvgpr_write_b32 %0, %1" : "=a"(ag[q * 8 + 1]) : "v"(wa.y));
            asm volatile("v_accvgpr_write_b32 %0, %1" : "=a"(ag[q * 8 + 2]) : "v"(wa.z));
            asm volatile("v_accvgpr_write_b32 %0, %1" : "=a"(ag[q * 8 + 3]) : "v"(wa.w));
            asm volatile("v_accvgpr_write_b32 %0, %1" : "=a"(ag[q * 8 + 4]) : "v"(wb.x));
            asm volatile("v_accvgpr_write_b32 %0, %1" : "=a"(ag[q * 8 + 5]) : "v"(wb.y));
            asm volatile("v_accvgpr_write_b32 %0, %1" : "=a"(ag[q * 8 + 6]) : "v"(wb.z));
            asm volatile("v_accvgpr_write_b32 %0, %1" : "=a"(ag[q * 8 + 7]) : "v"(wb.w));
        }

        float* st = state + ((size_t)layer * B_ + b) * 512;
        u16* hb16 = (u16*)hbuf_pk;
        float c_state = 0.f, h_last = 0.f;
        if (j < 256) {
            float h0 = (t0 == 0) ? 0.f : st[256 + j];
            c_state = (t0 == 0) ? 0.f : st[j];
            hb16[j] = fh(h0);
            h_last = h0;
        }
        __syncthreads();

        const u16* prow = pre + (size_t)(layer * MCH + b * TC_) * 1024;
        u16* encrow = enc + ((size_t)b * T_ + t0) * 512 + layer * 256;
        const uint4* hp4 = (const uint4*)hbuf_pk;

        for (int tt = 0; tt < TC_; ++tt, prow += 1024, encrow += 512) {
            u16 pA = prow[j], pB = prow[512 + j];
            float a0 = 0.f, a1 = 0.f, b0 = 0.f, b1 = 0.f;
#pragma unroll
            for (int m = 0; m < 9; ++m) {
                uint4 hh = hp4[m];
                a0 = fdot2(wrA[4 * m + 0], hh.x, a0);
                a1 = fdot2(wrA[4 * m + 1], hh.y, a1);
                a0 = fdot2(wrA[4 * m + 2], hh.z, a0);
                a1 = fdot2(wrA[4 * m + 3], hh.w, a1);
                b0 = fdot2(wrB[4 * m + 0], hh.x, b0);
                b1 = fdot2(wrB[4 * m + 1], hh.y, b1);
                b0 = fdot2(wrB[4 * m + 2], hh.z, b0);
                b1 = fdot2(wrB[4 * m + 3], hh.w, b1);
            }
#pragma unroll
            for (int m = 0; m < 9; ++m) {
                uint4 hh = hp4[9 + m];
                uint4 wa = wlA[m][j];
                uint4 wb = wlB[m][j];
                a0 = fdot2(wa.x, hh.x, a0); a1 = fdot2(wa.y, hh.y, a1);
                a0 = fdot2(wa.z, hh.z, a0); a1 = fdot2(wa.w, hh.w, a1);
                b0 = fdot2(wb.x, hh.x, b0); b1 = fdot2(wb.y, hh.y, b1);
                b0 = fdot2(wb.z, hh.z, b0); b1 = fdot2(wb.w, hh.w, b1);
            }
#pragma unroll
            for (int q = 0; q < 14; ++q) {
                uint4 hh = hp4[18 + q];
                u32 w0, w1, w2, w3, w4, w5, w6, w7;
                asm volatile("v_accvgpr_read_b32 %0, %1" : "=v"(w0) : "a"(ag[q * 8 + 0]));
                asm volatile("v_accvgpr_read_b32 %0, %1" : "=v"(w1) : "a"(ag[q * 8 + 1]));
                asm volatile("v_accvgpr_read_b32 %0, %1" : "=v"(w2) : "a"(ag[q * 8 + 2]));
                asm volatile("v_accvgpr_read_b32 %0, %1" : "=v"(w3) : "a"(ag[q * 8 + 3]));
                asm volatile("v_accvgpr_read_b32 %0, %1" : "=v"(w4) : "a"(ag[q * 8 + 4]));
                asm volatile("v_accvgpr_read_b32 %0, %1" : "=v"(w5) : "a"(ag[q * 8 + 5]));
                asm volatile("v_accvgpr_read_b32 %0, %1" : "=v"(w6) : "a"(ag[q * 8 + 6]));
                asm volatile("v_accvgpr_read_b32 %0, %1" : "=v"(w7) : "a"(ag[q * 8 + 7]));
                a0 = fdot2(w0, hh.x, a0); a1 = fdot2(w1, hh.y, a1);
                a0 = fdot2(w2, hh.z, a0); a1 = fdot2(w3, hh.w, a1);
                b0 = fdot2(w4, hh.x, b0); b1 = fdot2(w5, hh.y, b1);
                b0 = fdot2(w6, hh.z, b0); b1 = fdot2(w7, hh.w, b1);
            }
            float zA = (a0 + a1) + hf(pA);
            float zB = (b0 + b1) + hf(pB);
            zbuf[j] = sigf(zA);
            zbuf[512 + j] = (j < 256) ? tanhf(zB) : sigf(zB);
            __syncthreads();
            if (j < 256) {
                float gi = zbuf[j], gf = zbuf[256 + j], gg = zbuf[512 + j], go = zbuf[768 + j];
                c_state = gf * c_state + gi * gg;
                float h = go * tanhf(c_state);
                hb16[j] = fh(h);
                encrow[j] = fh(h);
                h_last = h;
            }
            __syncthreads();
        }
        if (j < 256) { st[j] = c_state; st[256 + j] = h_last; }
    } else {
        // ---------------------------- SMALL --------------------------------
        if (c >= NCH) return;
        const int chain = blockIdx.x - 128;
        const int b = chain >> 1;
        const int layer = chain & 1;

        float W4[4];
#pragma unroll
        for (int kk = 0; kk < 4; ++kk) W4[kk] = w4s[(layer * 4 + kk) * 512 + j];
        float beff = beffs[layer * 512 + j];
        u32 whp[64];
#pragma unroll
        for (int p = 0; p < 64; ++p) whp[p] = whs[(layer * 64 + p) * 512 + j];

        u16* hb16 = (u16*)hbs;
        float c_state = 0.f;
        if (j < 128) {
            if (c == 0) hb16[j] = 0;
            else { c_state = sstC[chain * 128 + j]; hb16[j] = sstH[chain * 128 + j]; }
        }
        const int t0 = c * TC_;
        const float* Xb = X + (size_t)b * T_;
        float xm1 = (t0 == 0) ? 0.f : Xb[t0 - 1];
        float x0 = Xb[t0], xp1 = Xb[t0 + 1], xp2 = Xb[t0 + 2];
        __syncthreads();

        const uint4* hp4 = (const uint4*)hbs;
        u16 hprev = 0;
        for (int t = t0; t < t0 + TC_; ++t) {
            float xnext = (t + 3 < T_) ? Xb[t + 3] : 0.f;

            float za = beff + xm1 * W4[0] + x0 * W4[1] + xp1 * W4[2] + xp2 * W4[3];
            float zb = 0.f, zc = 0.f, zd = 0.f;
#pragma unroll
            for (int m = 0; m < 16; ++m) {
                uint4 hh = hp4[m];
                za = fdot2(whp[4 * m + 0], hh.x, za);
                zb = fdot2(whp[4 * m + 1], hh.y, zb);
                zc = fdot2(whp[4 * m + 2], hh.z, zc);
                zd = fdot2(whp[4 * m + 3], hh.w, zd);
            }
            float z = (za + zb) + (zc + zd);
            zbuf[j] = (j >= 256 && j < 384) ? tanhf(z) : sigf(z);
            __syncthreads();
            if (j < 128) {
                float gi = zbuf[j], gf = zbuf[128 + j], gg = zbuf[256 + j], go = zbuf[384 + j];
                c_state = gf * c_state + gi * gg;
                float h = go * tanhf(c_state);
                hprev = fh(h);
                hb16[j] = hprev;
                x12[((size_t)b * T_ + t) * 256 + layer * 128 + j] = hprev;
            }
            xm1 = x0; x0 = xp1; xp1 = xp2; xp2 = xnext;
            __syncthreads();
        }
        if (j < 128) { sstC[chain * 128 + j] = c_state; sstH[chain * 128 + j] = hprev; }
    }
}

// ---------------------------------------------------------------------------
// MFMA fp16 GEMM (unchanged from r13 — layout verified by bit-identical absmax)
// ---------------------------------------------------------------------------
template<int OUTMODE, int CHUNK, int LAYERED>
__global__ __launch_bounds__(256) void gemm_mfma(
    const u16* __restrict__ A, const u32* __restrict__ B0, const u32* __restrict__ B1,
    const float* __restrict__ bias0, const float* __restrict__ bias1,
    void* __restrict__ outv, int t0, int N, int K)
{
    __shared__ __align__(16) u32 Al[128][20];   // [row][16 u32 k + 4 pad]
    __shared__ __align__(16) u32 Bl[128][20];   // [col][16 u32 k + 4 pad]
    const int tid = threadIdx.x;
    const int bx = blockIdx.x;
    const int layer = LAYERED ? (bx >> 6) : 0;
    const int m0 = LAYERED ? ((bx & 63) * 128) : (bx * 128);
    const int n0 = blockIdx.y * 128;
    const u32* Bpk = layer ? B1 : B0;
    const float* bias = layer ? bias1 : bias0;
    const int K2 = K >> 1;

    const int w = tid >> 6;
    const int lane = tid & 63;
    const int wr = (w >> 1) * 64, wc = (w & 1) * 64;
    const int lr = lane & 15, lg = lane >> 4;

    f32x4 acc[4][4];
#pragma unroll
    for (int r = 0; r < 4; ++r)
#pragma unroll
        for (int c = 0; c < 4; ++c) acc[r][c] = (f32x4){0.f, 0.f, 0.f, 0.f};

    for (int k0 = 0; k0 < K; k0 += 32) {
        const int kp0 = k0 >> 1;
#pragma unroll
        for (int it = 0; it < 2; ++it) {
            int idx = tid + it * 256;
            int row = idx >> 2, q = idx & 3;
            int grow = m0 + row;
            size_t garow = CHUNK ? ((size_t)(grow >> 7) * T_ + t0 + (grow & 127)) : (size_t)grow;
            uint4 ua = *(const uint4*)(A + garow * K + k0 + q * 8);
            *(uint4*)&Al[row][q * 4] = ua;
            uint4 ub = *(const uint4*)(Bpk + (size_t)(n0 + row) * K2 + kp0 + q * 4);
            *(uint4*)&Bl[row][q * 4] = ub;
        }
        __syncthreads();
        half8 bfr[4];
#pragma unroll
        for (int c = 0; c < 4; ++c) {
            const u32* bp = &Bl[wc + c * 16 + lr][0];
            uint2 blo = *(const uint2*)(bp + 2 * lg);
            uint2 bhi = *(const uint2*)(bp + 8 + 2 * lg);
            uint4 bf = make_uint4(blo.x, blo.y, bhi.x, bhi.y);
            bfr[c] = __builtin_bit_cast(half8, bf);
        }
#pragma unroll
        for (int r = 0; r < 4; ++r) {
            const u32* ap = &Al[wr + r * 16 + lr][0];
            uint2 alo = *(const uint2*)(ap + 2 * lg);
            uint2 ahi = *(const uint2*)(ap + 8 + 2 * lg);
            uint4 af = make_uint4(alo.x, alo.y, ahi.x, ahi.y);
            half8 av = __builtin_bit_cast(half8, af);
#pragma unroll
            for (int c = 0; c < 4; ++c)
                acc[r][c] = __builtin_amdgcn_mfma_f32_16x16x32_f16(av, bfr[c], acc[r][c], 0, 0, 0);
        }
        __syncthreads();
    }

    if (OUTMODE == 0) {
        u16* outp = (u16*)outv + (LAYERED ? (size_t)layer * MCH * 1024 : 0);
#pragma unroll
        for (int c = 0; c < 4; ++c) {
            int col = n0 + wc + c * 16 + lr;
            float bvs = bias[col];
#pragma unroll
            for (int r = 0; r < 4; ++r) {
                int orow = m0 + wr + r * 16 + 4 * lg;
#pragma unroll
                for (int i = 0; i < 4; ++i)
                    outp[(size_t)(orow + i) * N + col] = fh(acc[r][c][i] + bvs);
            }
        }
    } else {
        float* outp = (float*)outv;
#pragma unroll
        for (int c = 0; c < 4; ++c) {
            int col = n0 + wc + c * 16 + lr;
            float bvs = bias[col];
#pragma unroll
            for (int r = 0; r < 4; ++r) {
                int orow = m0 + wr + r * 16 + 4 * lg;
#pragma unroll
                for (int i = 0; i < 4; ++i)
                    outp[(size_t)(orow + i) * N + col] = tanhf(acc[r][c][i] + bvs);
            }
        }
    }
}

// ---------------------------------------------------------------------------
// Attention pooling + head, one workgroup per batch. (unchanged)
// ---------------------------------------------------------------------------
__global__ __launch_bounds__(256) void attn_head(
    const float* __restrict__ S1, const u16* __restrict__ enc,
    const float* __restrict__ attV, const float* __restrict__ attVb,
    const float* __restrict__ d1W, const float* __restrict__ d1b,
    const float* __restrict__ d2W, const float* __restrict__ d2b,
    float* __restrict__ out)
{
    const int b = blockIdx.x;
    const int tid = threadIdx.x;
    const int lane = tid & 63, w = tid >> 6;

    __shared__ float sb[1024];
    __shared__ float red[32];
    __shared__ __align__(16) float ctx[512];
    __shared__ float h1s[128];

    float av0 = attV[lane], av1 = attV[64 + lane];
    const float* S1b = S1 + (size_t)b * T_ * 128;
    for (int it = 0; it < 256; ++it) {
        int t = it * 4 + w;
        const float* row = S1b + (size_t)t * 128;
        float p = row[lane] * av0 + row[64 + lane] * av1;
#pragma unroll
        for (int off = 32; off > 0; off >>= 1) p += __shfl_down(p, off);
        if (lane == 0) sb[t] = p + attVb[0];
    }
    __syncthreads();

    float mx = -3.0e38f;
#pragma unroll
    for (int q = 0; q < 4; ++q) mx = fmaxf(mx, sb[tid + 256 * q]);
#pragma unroll
    for (int off = 32; off > 0; off >>= 1) mx = fmaxf(mx, __shfl_down(mx, off));
    if (lane == 0) red[w] = mx;
    __syncthreads();
    if (tid == 0) red[8] = fmaxf(fmaxf(red[0], red[1]), fmaxf(red[2], red[3]));
    __syncthreads();
    float bm = red[8];
    float s = 0.f;
#pragma unroll
    for (int q = 0; q < 4; ++q) {
        float e = expf(sb[tid + 256 * q] - bm);
        sb[tid + 256 * q] = e;
        s += e;
    }
#pragma unroll
    for (int off = 32; off > 0; off >>= 1) s += __shfl_down(s, off);
    if (lane == 0) red[16 + w] = s;
    __syncthreads();
    if (tid == 0) red[24] = 1.0f / (red[16] + red[17] + red[18] + red[19]);
    __syncthreads();
    float inv = red[24];
#pragma unroll
    for (int q = 0; q < 4; ++q) sb[tid + 256 * q] *= inv;
    __syncthreads();

    const u16* encb = enc + (size_t)b * T_ * 512;
    float a0 = 0.f, a1 = 0.f;
    for (int t = 0; t < T_; ++t) {
        float wt = sb[t];
        a0 += wt * hf(encb[(size_t)t * 512 + tid]);
        a1 += wt * hf(encb[(size_t)t * 512 + 256 + tid]);
    }
    ctx[tid] = a0;
    ctx[256 + tid] = a1;
    __syncthreads();

    if (tid < 128) {
        float s1 = d1b[tid];
        for (int k = 0; k < 512; ++k) s1 += ctx[k] * d1W[k * 128 + tid];
        h1s[tid] = tanhf(s1);
    }
    __syncthreads();
    if (tid < 128) {
        float p = h1s[tid] * d2W[tid];
#pragma unroll
        for (int off = 32; off > 0; off >>= 1) p += __shfl_down(p, off);
        if ((tid & 63) == 0) red[28 + (tid >> 6)] = p;
    }
    __syncthreads();
    if (tid == 0) out[b] = red[28] + red[29] + d2b[0];
}

// ---------------------------------------------------------------------------
extern "C" void kernel_launch(void* const* d_in, const int* in_sizes, int n_in,
                              void* d_out, int out_size, void* d_ws, size_t ws_size,
                              hipStream_t stream)
{
    const float* X    = (const float*)d_in[0];
    const float* cw   = (const float*)d_in[1];
    const float* cb   = (const float*)d_in[2];
    const float* Wi1  = (const float*)d_in[3];
    const float* Wh1  = (const float*)d_in[4];
    const float* b1   = (const float*)d_in[5];
    const float* Wi2  = (const float*)d_in[6];
    const float* Wh2  = (const float*)d_in[7];
    const float* b2   = (const float*)d_in[8];
    const float* Wi3  = (const float*)d_in[9];
    const float* Wh3  = (const float*)d_in[10];
    const float* b3   = (const float*)d_in[11];
    const float* Wi4  = (const float*)d_in[12];
    const float* Wh4  = (const float*)d_in[13];
    const float* b4   = (const float*)d_in[14];
    const float* attW = (const float*)d_in[15];
    const float* attWb= (const float*)d_in[16];
    const float* attV = (const float*)d_in[17];
    const float* attVb= (const float*)d_in[18];
    const float* d1W  = (const float*)d_in[19];
    const float* d1b  = (const float*)d_in[20];
    const float* d2W  = (const float*)d_in[21];
    const float* d2b  = (const float*)d_in[22];
    float* out = (float*)d_out;

    // workspace layout (total 137,547,776 B ~ 131.2 MiB — under r2's proven 169 MB):
    char* w = (char*)d_ws;
    u16*   x12  = (u16*)w;                          // 33,554,432
    u16*   pre  = (u16*)(w + 33554432);             // 33,554,432 (per chunk, 2 layers)
    u16*   enc  = (u16*)(w + 67108864);             // 67,108,864
    u32*   wpk  = (u32*)(w + 134217728);            //  1,048,576
    float* state= (float*)(w + 135266304);          //    262,144
    u32*   wi3T = (u32*)(w + 135528448);            //    524,288
    u32*   wi4T = (u32*)(w + 136052736);            //    524,288
    u32*   awT  = (u32*)(w + 136577024);            //    131,072
    uint4* wpkT = (uint4*)(w + 136708096);          //    458,752
    u32*   whs  = (u32*)(w + 137166848);            //    262,144
    float* w4s  = (float*)(w + 137428992);          //     16,384
    float* beffs= (float*)(w + 137445376);          //      4,096
    float* sstC = (float*)(w + 137449472);          //     65,536
    u16*   sstH = (u16*)(w + 137515008);            //     32,768
    float* S1   = (float*)(w + 33554432);           // 32 MiB, aliases pre (dead after chunks)

    cvt_all<<<2548, 256, 0, stream>>>(Wh3, Wh4, Wi3, Wi4, attW, Wh1, Wh2, cw, cb,
                                      Wi1, Wi2, b1, b2,
                                      wpk, wi3T, wi4T, awT, wpkT, whs, w4s, beffs);

    for (int c = 0; c <= NCH; ++c) {
        fused_step<<<256, 512, 0, stream>>>(pre, wpk, wpkT, state, enc,
                                            X, whs, w4s, beffs, sstC, sstH, x12, c);
        if (c < NCH)
            gemm_mfma<0, 1, 1><<<dim3(128, 8), 256, 0, stream>>>(
                x12, wi3T, wi4T, b3, b4, pre, c * TC_, 1024, 256);
    }

    gemm_mfma<1, 0, 0><<<dim3(512, 1), 256, 0, stream>>>(
        enc, awT, awT, attWb, attWb, S1, 0, 128, 512);
    attn_head<<<64, 256, 0, stream>>>(S1, enc, attV, attVb, d1W, d1b, d2W, d2b, out);
}

// Round 16
// 3179.352 us; speedup vs baseline: 1.0679x; 1.0679x over previous
//
#include <hip/hip_runtime.h>
#include <hip/hip_fp16.h>

// Sizes fixed by the problem.
#define B_   64
#define T_   1024
#define H1_  128
#define H2_  256
#define TC_  128              // time-chunk for LSTM3/4 and LSTM1/2
#define NCH  (T_ / TC_)       // 8 chunks
#define MCH  (B_ * TC_)       // 8192 rows per chunk per layer

typedef unsigned int  u32;
typedef unsigned short u16;
typedef _Float16 half2_t __attribute__((ext_vector_type(2)));
typedef _Float16 half8 __attribute__((ext_vector_type(8)));
typedef float f32x4 __attribute__((ext_vector_type(4)));

__device__ __forceinline__ float fdot2(u32 w, u32 h, float acc) {
    return __builtin_amdgcn_fdot2(__builtin_bit_cast(half2_t, w),
                                  __builtin_bit_cast(half2_t, h), acc, false);
}
__device__ __forceinline__ u32 pk2(float a, float b) {
    __half2 h = __floats2half2_rn(a, b);
    return __builtin_bit_cast(u32, h);
}
__device__ __forceinline__ float hf(u16 u) { return __half2float(__builtin_bit_cast(__half, u)); }
__device__ __forceinline__ u16 fh(float f) { return __builtin_bit_cast(u16, __float2half(f)); }
__device__ __forceinline__ float sigf(float x) { return 1.0f / (1.0f + expf(-x)); }

// AGPR park/read. VOP3P can't source AGPRs directly (r15 assembler reject),
// so reads go through v_accvgpr_read — but SOFTWARE-PIPELINED: group g+1's
// reads issue before group g's fdot2s, so read latency hides under compute
// (r14's mistake was read->use back-to-back, +1260 cy/step).
#define AG_RD(dst, idx) asm volatile("v_accvgpr_read_b32 %0, %1" : "=v"(dst) : "a"(ag[idx]))
#define AG_WR(idx, src) asm volatile("v_accvgpr_write_b32 %0, %1" : "=a"(ag[idx]) : "v"(src))

// ---------------------------------------------------------------------------
// Weight conversions (packed fp16 pairs) + small-LSTM prologue precompute:
//  wpk  [2][128][1024]: Wh3/Wh4 pairs (k2, col j)
//  wi3T/wi4T/awT:       MFMA B operands, N-major (flip baked into wi4T)
//  wpkT [2][15][1024]:  Wh3/Wh4 pairs k2=68..127 lane-contiguous uint4 (AGPR park)
//  whs  [2][64][512]:   Wh1/Wh2 pairs
//  w4s, beffs:          conv-folded taps/bias
// ---------------------------------------------------------------------------
__global__ void cvt_all(const float* __restrict__ Wh3, const float* __restrict__ Wh4,
                        const float* __restrict__ Wi3, const float* __restrict__ Wi4,
                        const float* __restrict__ attW,
                        const float* __restrict__ Wh1, const float* __restrict__ Wh2,
                        const float* __restrict__ cw, const float* __restrict__ cb,
                        const float* __restrict__ Wi1, const float* __restrict__ Wi2,
                        const float* __restrict__ b1, const float* __restrict__ b2,
                        u32* __restrict__ wpk, u32* __restrict__ wi3T,
                        u32* __restrict__ wi4T, u32* __restrict__ awT,
                        uint4* __restrict__ wpkT, u32* __restrict__ whs,
                        float* __restrict__ w4s, float* __restrict__ beffs)
{
    int idx = blockIdx.x * 256 + threadIdx.x;   // < 654336
    if (idx < 262144) {
        int l = idx >> 17, rem = idx & 131071, k2 = rem >> 10, j = rem & 1023;
        const float* W = l ? Wh4 : Wh3;
        wpk[idx] = pk2(W[(2 * k2) * 1024 + j], W[(2 * k2 + 1) * 1024 + j]);
    } else if (idx < 393216) {
        int rel = idx - 262144, n = rel >> 7, kp = rel & 127;   // [n][kp]
        wi3T[rel] = pk2(Wi3[(2 * kp) * 1024 + n], Wi3[(2 * kp + 1) * 1024 + n]);
    } else if (idx < 524288) {
        int rel = idx - 393216, n = rel >> 7, kp = rel & 127;   // [n][kp], flip
        wi4T[rel] = pk2(Wi4[(255 - 2 * kp) * 1024 + n], Wi4[(254 - 2 * kp) * 1024 + n]);
    } else if (idx < 557056) {
        int rel = idx - 524288, n = rel >> 8, kp = rel & 255;   // [n][kp]
        awT[rel] = pk2(attW[(2 * kp) * 128 + n], attW[(2 * kp + 1) * 128 + n]);
    } else if (idx < 587776) {
        int rel = idx - 557056;          // < 30720 = 2 * 15 * 1024
        int l = rel / 15360;
        int rem = rel - l * 15360;
        int q = rem >> 10, col = rem & 1023;
        const float* W = l ? Wh4 : Wh3;
        int k2 = 68 + 4 * q;
        uint4 v;
        v.x = pk2(W[(2 * k2 + 0) * 1024 + col], W[(2 * k2 + 1) * 1024 + col]);
        v.y = pk2(W[(2 * k2 + 2) * 1024 + col], W[(2 * k2 + 3) * 1024 + col]);
        v.z = pk2(W[(2 * k2 + 4) * 1024 + col], W[(2 * k2 + 5) * 1024 + col]);
        v.w = pk2(W[(2 * k2 + 6) * 1024 + col], W[(2 * k2 + 7) * 1024 + col]);
        wpkT[rel] = v;
    } else if (idx < 653312) {
        int rel = idx - 587776;          // < 65536 = 2 * 64 * 512
        int l = rel >> 15, rem = rel & 32767, p = rem >> 9, col = rem & 511;
        const float* W = l ? Wh2 : Wh1;
        whs[rel] = pk2(W[(2 * p) * 512 + col], W[(2 * p + 1) * 512 + col]);
    } else if (idx < 654336) {
        int rel = idx - 653312;          // < 1024
        int l = rel >> 9, col = rel & 511;
        const float* Wi = l ? Wi2 : Wi1;
        const float* bb = l ? b2 : b1;
#pragma unroll
        for (int kk = 0; kk < 4; ++kk) {
            float s = 0.f;
#pragma unroll
            for (int c0 = 0; c0 < 16; ++c0) {
                int cc = l ? (15 - c0) : c0;
                s += cw[kk * 16 + c0] * Wi[cc * 512 + col];
            }
            w4s[(l * 4 + kk) * 512 + col] = s;
        }
        float be = bb[col];
#pragma unroll
        for (int c0 = 0; c0 < 16; ++c0) {
            int cc = l ? (15 - c0) : c0;
            be += cb[c0] * Wi[cc * 512 + col];
        }
        beffs[l * 512 + col] = be;
    }
}

// ---------------------------------------------------------------------------
// FUSED persistent step: 256 blocks, 512 threads.
//  blocks   0..127: LSTM3/4 (big) chunk c-1  (skipped when c == 0)
//  blocks 128..255: LSTM1/2 (small) chunk c  (skipped when c == NCH)
// Big weight residency per column (128 packed pairs):
//   k2  0..31  -> VGPR  (32/col, 64/thread)
//   k2 32..67  -> LDS   (147 KB uint4 conflict-free)
//   k2 68..127 -> AGPR  (60/col, 120/thread) read via pipelined accvgpr_read
// => ZERO per-step global weight stream (r13's binding 3450 cy L2-port cost).
// ---------------------------------------------------------------------------
__global__ __launch_bounds__(512) void fused_step(
    const u16* __restrict__ pre, const u32* __restrict__ wpk,
    const uint4* __restrict__ wpkT, float* __restrict__ state,
    u16* __restrict__ enc,
    const float* __restrict__ X, const u32* __restrict__ whs,
    const float* __restrict__ w4s, const float* __restrict__ beffs,
    float* __restrict__ sstC, u16* __restrict__ sstH,
    u16* __restrict__ x12, int c)
{
    __shared__ __align__(16) uint4 wlA[9][512];
    __shared__ __align__(16) uint4 wlB[9][512];
    __shared__ __align__(16) u32 hbuf_pk[128];
    __shared__ float zbuf[1024];
    __shared__ __align__(16) u32 hbs[64];

    const int j = threadIdx.x;

    if (blockIdx.x < 128) {
        // ----------------------------- BIG ---------------------------------
        if (c == 0) return;
        const int t0 = (c - 1) * TC_;
        const int blk = blockIdx.x;
        const int b = blk >> 1;
        const int layer = blk & 1;

        const u32* wp = wpk + (size_t)layer * 131072;
        u32 wrA[32], wrB[32];
#pragma unroll
        for (int q = 0; q < 32; ++q) {
            wrA[q] = wp[q * 1024 + j];
            wrB[q] = wp[q * 1024 + 512 + j];
        }
#pragma unroll
        for (int m = 0; m < 9; ++m) {          // pairs 32..67 -> LDS
            uint4 va, vb;
            va.x = wp[(32 + 4 * m + 0) * 1024 + j];
            va.y = wp[(32 + 4 * m + 1) * 1024 + j];
            va.z = wp[(32 + 4 * m + 2) * 1024 + j];
            va.w = wp[(32 + 4 * m + 3) * 1024 + j];
            vb.x = wp[(32 + 4 * m + 0) * 1024 + 512 + j];
            vb.y = wp[(32 + 4 * m + 1) * 1024 + 512 + j];
            vb.z = wp[(32 + 4 * m + 2) * 1024 + 512 + j];
            vb.w = wp[(32 + 4 * m + 3) * 1024 + 512 + j];
            wlA[m][j] = va;
            wlB[m][j] = vb;
        }
        // pairs 68..127 -> 120 AGPRs (one-time prologue).
        const uint4* wt = wpkT + (size_t)layer * 15360;
        u32 ag[120];
#pragma unroll
        for (int q = 0; q < 15; ++q) {
            uint4 wa = wt[q * 1024 + j];
            uint4 wb = wt[q * 1024 + 512 + j];
            AG_WR(q * 8 + 0, wa.x); AG_WR(q * 8 + 1, wa.y);
            AG_WR(q * 8 + 2, wa.z); AG_WR(q * 8 + 3, wa.w);
            AG_WR(q * 8 + 4, wb.x); AG_WR(q * 8 + 5, wb.y);
            AG_WR(q * 8 + 6, wb.z); AG_WR(q * 8 + 7, wb.w);
        }

        float* st = state + ((size_t)layer * B_ + b) * 512;
        u16* hb16 = (u16*)hbuf_pk;
        float c_state = 0.f, h_last = 0.f;
        if (j < 256) {
            float h0 = (t0 == 0) ? 0.f : st[256 + j];
            c_state = (t0 == 0) ? 0.f : st[j];
            hb16[j] = fh(h0);
            h_last = h0;
        }
        __syncthreads();

        const u16* prow = pre + (size_t)(layer * MCH + b * TC_) * 1024;
        u16* encrow = enc + ((size_t)b * T_ + t0) * 512 + layer * 256;
        const uint4* hp4 = (const uint4*)hbuf_pk;

        for (int tt = 0; tt < TC_; ++tt, prow += 1024, encrow += 512) {
            u16 pA = prow[j], pB = prow[512 + j];
            float a0 = 0.f, a1 = 0.f, b0 = 0.f, b1 = 0.f;
            u32 wb0[8], wb1[8];
            // preload AGPR group 0: latency hides under the VGPR fdot2 section
            AG_RD(wb0[0], 0); AG_RD(wb0[1], 1); AG_RD(wb0[2], 2); AG_RD(wb0[3], 3);
            AG_RD(wb0[4], 4); AG_RD(wb0[5], 5); AG_RD(wb0[6], 6); AG_RD(wb0[7], 7);
#pragma unroll
            for (int m = 0; m < 8; ++m) {       // pairs 0..31 from VGPR
                uint4 hh = hp4[m];
                a0 = fdot2(wrA[4 * m + 0], hh.x, a0);
                a1 = fdot2(wrA[4 * m + 1], hh.y, a1);
                a0 = fdot2(wrA[4 * m + 2], hh.z, a0);
                a1 = fdot2(wrA[4 * m + 3], hh.w, a1);
                b0 = fdot2(wrB[4 * m + 0], hh.x, b0);
                b1 = fdot2(wrB[4 * m + 1], hh.y, b1);
                b0 = fdot2(wrB[4 * m + 2], hh.z, b0);
                b1 = fdot2(wrB[4 * m + 3], hh.w, b1);
            }
#pragma unroll
            for (int m = 0; m < 9; ++m) {       // pairs 32..67 from LDS
                uint4 hh = hp4[8 + m];
                uint4 wa = wlA[m][j];
                uint4 wb = wlB[m][j];
                a0 = fdot2(wa.x, hh.x, a0); a1 = fdot2(wa.y, hh.y, a1);
                a0 = fdot2(wa.z, hh.z, a0); a1 = fdot2(wa.w, hh.w, a1);
                b0 = fdot2(wb.x, hh.x, b0); b1 = fdot2(wb.y, hh.y, b1);
                b0 = fdot2(wb.z, hh.z, b0); b1 = fdot2(wb.w, hh.w, b1);
            }
            // pairs 68..127 from AGPRs, 2-stage pipelined reads
#define AG_GROUP(CUR, NXT, G)                                                  \
            do {                                                               \
                uint4 hh = hp4[17 + (G)];                                      \
                if ((G) < 14) {                                                \
                    AG_RD(NXT[0], ((G) + 1) * 8 + 0);                          \
                    AG_RD(NXT[1], ((G) + 1) * 8 + 1);                          \
                    AG_RD(NXT[2], ((G) + 1) * 8 + 2);                          \
                    AG_RD(NXT[3], ((G) + 1) * 8 + 3);                          \
                    AG_RD(NXT[4], ((G) + 1) * 8 + 4);                          \
                    AG_RD(NXT[5], ((G) + 1) * 8 + 5);                          \
                    AG_RD(NXT[6], ((G) + 1) * 8 + 6);                          \
                    AG_RD(NXT[7], ((G) + 1) * 8 + 7);                          \
                }                                                              \
                a0 = fdot2(CUR[0], hh.x, a0); a1 = fdot2(CUR[1], hh.y, a1);    \
                a0 = fdot2(CUR[2], hh.z, a0); a1 = fdot2(CUR[3], hh.w, a1);    \
                b0 = fdot2(CUR[4], hh.x, b0); b1 = fdot2(CUR[5], hh.y, b1);    \
                b0 = fdot2(CUR[6], hh.z, b0); b1 = fdot2(CUR[7], hh.w, b1);    \
            } while (0)
            AG_GROUP(wb0, wb1, 0);  AG_GROUP(wb1, wb0, 1);
            AG_GROUP(wb0, wb1, 2);  AG_GROUP(wb1, wb0, 3);
            AG_GROUP(wb0, wb1, 4);  AG_GROUP(wb1, wb0, 5);
            AG_GROUP(wb0, wb1, 6);  AG_GROUP(wb1, wb0, 7);
            AG_GROUP(wb0, wb1, 8);  AG_GROUP(wb1, wb0, 9);
            AG_GROUP(wb0, wb1, 10); AG_GROUP(wb1, wb0, 11);
            AG_GROUP(wb0, wb1, 12); AG_GROUP(wb1, wb0, 13);
            AG_GROUP(wb0, wb1, 14);
#undef AG_GROUP
            float zA = (a0 + a1) + hf(pA);
            float zB = (b0 + b1) + hf(pB);
            zbuf[j] = sigf(zA);
            zbuf[512 + j] = (j < 256) ? tanhf(zB) : sigf(zB);
            __syncthreads();
            if (j < 256) {
                float gi = zbuf[j], gf = zbuf[256 + j], gg = zbuf[512 + j], go = zbuf[768 + j];
                c_state = gf * c_state + gi * gg;
                float h = go * tanhf(c_state);
                hb16[j] = fh(h);
                encrow[j] = fh(h);
                h_last = h;
            }
            __syncthreads();
        }
        if (j < 256) { st[j] = c_state; st[256 + j] = h_last; }
    } else {
        // ---------------------------- SMALL --------------------------------
        if (c >= NCH) return;
        const int chain = blockIdx.x - 128;
        const int b = chain >> 1;
        const int layer = chain & 1;

        float W4[4];
#pragma unroll
        for (int kk = 0; kk < 4; ++kk) W4[kk] = w4s[(layer * 4 + kk) * 512 + j];
        float beff = beffs[layer * 512 + j];
        u32 whp[64];
#pragma unroll
        for (int p = 0; p < 64; ++p) whp[p] = whs[(layer * 64 + p) * 512 + j];

        u16* hb16 = (u16*)hbs;
        float c_state = 0.f;
        if (j < 128) {
            if (c == 0) hb16[j] = 0;
            else { c_state = sstC[chain * 128 + j]; hb16[j] = sstH[chain * 128 + j]; }
        }
        const int t0 = c * TC_;
        const float* Xb = X + (size_t)b * T_;
        float xm1 = (t0 == 0) ? 0.f : Xb[t0 - 1];
        float x0 = Xb[t0], xp1 = Xb[t0 + 1], xp2 = Xb[t0 + 2];
        __syncthreads();

        const uint4* hp4 = (const uint4*)hbs;
        u16 hprev = 0;
        for (int t = t0; t < t0 + TC_; ++t) {
            float xnext = (t + 3 < T_) ? Xb[t + 3] : 0.f;

            float za = beff + xm1 * W4[0] + x0 * W4[1] + xp1 * W4[2] + xp2 * W4[3];
            float zb = 0.f, zc = 0.f, zd = 0.f;
#pragma unroll
            for (int m = 0; m < 16; ++m) {
                uint4 hh = hp4[m];
                za = fdot2(whp[4 * m + 0], hh.x, za);
                zb = fdot2(whp[4 * m + 1], hh.y, zb);
                zc = fdot2(whp[4 * m + 2], hh.z, zc);
                zd = fdot2(whp[4 * m + 3], hh.w, zd);
            }
            float z = (za + zb) + (zc + zd);
            zbuf[j] = (j >= 256 && j < 384) ? tanhf(z) : sigf(z);
            __syncthreads();
            if (j < 128) {
                float gi = zbuf[j], gf = zbuf[128 + j], gg = zbuf[256 + j], go = zbuf[384 + j];
                c_state = gf * c_state + gi * gg;
                float h = go * tanhf(c_state);
                hprev = fh(h);
                hb16[j] = hprev;
                x12[((size_t)b * T_ + t) * 256 + layer * 128 + j] = hprev;
            }
            xm1 = x0; x0 = xp1; xp1 = xp2; xp2 = xnext;
            __syncthreads();
        }
        if (j < 128) { sstC[chain * 128 + j] = c_state; sstH[chain * 128 + j] = hprev; }
    }
}

// ---------------------------------------------------------------------------
// MFMA fp16 GEMM (unchanged from r13 — layout verified by bit-identical absmax)
// ---------------------------------------------------------------------------
template<int OUTMODE, int CHUNK, int LAYERED>
__global__ __launch_bounds__(256) void gemm_mfma(
    const u16* __restrict__ A, const u32* __restrict__ B0, const u32* __restrict__ B1,
    const float* __restrict__ bias0, const float* __restrict__ bias1,
    void* __restrict__ outv, int t0, int N, int K)
{
    __shared__ __align__(16) u32 Al[128][20];   // [row][16 u32 k + 4 pad]
    __shared__ __align__(16) u32 Bl[128][20];   // [col][16 u32 k + 4 pad]
    const int tid = threadIdx.x;
    const int bx = blockIdx.x;
    const int layer = LAYERED ? (bx >> 6) : 0;
    const int m0 = LAYERED ? ((bx & 63) * 128) : (bx * 128);
    const int n0 = blockIdx.y * 128;
    const u32* Bpk = layer ? B1 : B0;
    const float* bias = layer ? bias1 : bias0;
    const int K2 = K >> 1;

    const int w = tid >> 6;
    const int lane = tid & 63;
    const int wr = (w >> 1) * 64, wc = (w & 1) * 64;
    const int lr = lane & 15, lg = lane >> 4;

    f32x4 acc[4][4];
#pragma unroll
    for (int r = 0; r < 4; ++r)
#pragma unroll
        for (int c = 0; c < 4; ++c) acc[r][c] = (f32x4){0.f, 0.f, 0.f, 0.f};

    for (int k0 = 0; k0 < K; k0 += 32) {
        const int kp0 = k0 >> 1;
#pragma unroll
        for (int it = 0; it < 2; ++it) {
            int idx = tid + it * 256;
            int row = idx >> 2, q = idx & 3;
            int grow = m0 + row;
            size_t garow = CHUNK ? ((size_t)(grow >> 7) * T_ + t0 + (grow & 127)) : (size_t)grow;
            uint4 ua = *(const uint4*)(A + garow * K + k0 + q * 8);
            *(uint4*)&Al[row][q * 4] = ua;
            uint4 ub = *(const uint4*)(Bpk + (size_t)(n0 + row) * K2 + kp0 + q * 4);
            *(uint4*)&Bl[row][q * 4] = ub;
        }
        __syncthreads();
        half8 bfr[4];
#pragma unroll
        for (int c = 0; c < 4; ++c) {
            const u32* bp = &Bl[wc + c * 16 + lr][0];
            uint2 blo = *(const uint2*)(bp + 2 * lg);
            uint2 bhi = *(const uint2*)(bp + 8 + 2 * lg);
            uint4 bf = make_uint4(blo.x, blo.y, bhi.x, bhi.y);
            bfr[c] = __builtin_bit_cast(half8, bf);
        }
#pragma unroll
        for (int r = 0; r < 4; ++r) {
            const u32* ap = &Al[wr + r * 16 + lr][0];
            uint2 alo = *(const uint2*)(ap + 2 * lg);
            uint2 ahi = *(const uint2*)(ap + 8 + 2 * lg);
            uint4 af = make_uint4(alo.x, alo.y, ahi.x, ahi.y);
            half8 av = __builtin_bit_cast(half8, af);
#pragma unroll
            for (int c = 0; c < 4; ++c)
                acc[r][c] = __builtin_amdgcn_mfma_f32_16x16x32_f16(av, bfr[c], acc[r][c], 0, 0, 0);
        }
        __syncthreads();
    }

    if (OUTMODE == 0) {
        u16* outp = (u16*)outv + (LAYERED ? (size_t)layer * MCH * 1024 : 0);
#pragma unroll
        for (int c = 0; c < 4; ++c) {
            int col = n0 + wc + c * 16 + lr;
            float bvs = bias[col];
#pragma unroll
            for (int r = 0; r < 4; ++r) {
                int orow = m0 + wr + r * 16 + 4 * lg;
#pragma unroll
                for (int i = 0; i < 4; ++i)
                    outp[(size_t)(orow + i) * N + col] = fh(acc[r][c][i] + bvs);
            }
        }
    } else {
        float* outp = (float*)outv;
#pragma unroll
        for (int c = 0; c < 4; ++c) {
            int col = n0 + wc + c * 16 + lr;
            float bvs = bias[col];
#pragma unroll
            for (int r = 0; r < 4; ++r) {
                int orow = m0 + wr + r * 16 + 4 * lg;
#pragma unroll
                for (int i = 0; i < 4; ++i)
                    outp[(size_t)(orow + i) * N + col] = tanhf(acc[r][c][i] + bvs);
            }
        }
    }
}

// ---------------------------------------------------------------------------
// Attention pooling + head, one workgroup per batch. (unchanged)
// ---------------------------------------------------------------------------
__global__ __launch_bounds__(256) void attn_head(
    const float* __restrict__ S1, const u16* __restrict__ enc,
    const float* __restrict__ attV, const float* __restrict__ attVb,
    const float* __restrict__ d1W, const float* __restrict__ d1b,
    const float* __restrict__ d2W, const float* __restrict__ d2b,
    float* __restrict__ out)
{
    const int b = blockIdx.x;
    const int tid = threadIdx.x;
    const int lane = tid & 63, w = tid >> 6;

    __shared__ float sb[1024];
    __shared__ float red[32];
    __shared__ __align__(16) float ctx[512];
    __shared__ float h1s[128];

    float av0 = attV[lane], av1 = attV[64 + lane];
    const float* S1b = S1 + (size_t)b * T_ * 128;
    for (int it = 0; it < 256; ++it) {
        int t = it * 4 + w;
        const float* row = S1b + (size_t)t * 128;
        float p = row[lane] * av0 + row[64 + lane] * av1;
#pragma unroll
        for (int off = 32; off > 0; off >>= 1) p += __shfl_down(p, off);
        if (lane == 0) sb[t] = p + attVb[0];
    }
    __syncthreads();

    float mx = -3.0e38f;
#pragma unroll
    for (int q = 0; q < 4; ++q) mx = fmaxf(mx, sb[tid + 256 * q]);
#pragma unroll
    for (int off = 32; off > 0; off >>= 1) mx = fmaxf(mx, __shfl_down(mx, off));
    if (lane == 0) red[w] = mx;
    __syncthreads();
    if (tid == 0) red[8] = fmaxf(fmaxf(red[0], red[1]), fmaxf(red[2], red[3]));
    __syncthreads();
    float bm = red[8];
    float s = 0.f;
#pragma unroll
    for (int q = 0; q < 4; ++q) {
        float e = expf(sb[tid + 256 * q] - bm);
        sb[tid + 256 * q] = e;
        s += e;
    }
#pragma unroll
    for (int off = 32; off > 0; off >>= 1) s += __shfl_down(s, off);
    if (lane == 0) red[16 + w] = s;
    __syncthreads();
    if (tid == 0) red[24] = 1.0f / (red[16] + red[17] + red[18] + red[19]);
    __syncthreads();
    float inv = red[24];
#pragma unroll
    for (int q = 0; q < 4; ++q) sb[tid + 256 * q] *= inv;
    __syncthreads();

    const u16* encb = enc + (size_t)b * T_ * 512;
    float a0 = 0.f, a1 = 0.f;
    for (int t = 0; t < T_; ++t) {
        float wt = sb[t];
        a0 += wt * hf(encb[(size_t)t * 512 + tid]);
        a1 += wt * hf(encb[(size_t)t * 512 + 256 + tid]);
    }
    ctx[tid] = a0;
    ctx[256 + tid] = a1;
    __syncthreads();

    if (tid < 128) {
        float s1 = d1b[tid];
        for (int k = 0; k < 512; ++k) s1 += ctx[k] * d1W[k * 128 + tid];
        h1s[tid] = tanhf(s1);
    }
    __syncthreads();
    if (tid < 128) {
        float p = h1s[tid] * d2W[tid];
#pragma unroll
        for (int off = 32; off > 0; off >>= 1) p += __shfl_down(p, off);
        if ((tid & 63) == 0) red[28 + (tid >> 6)] = p;
    }
    __syncthreads();
    if (tid == 0) out[b] = red[28] + red[29] + d2b[0];
}

// ---------------------------------------------------------------------------
extern "C" void kernel_launch(void* const* d_in, const int* in_sizes, int n_in,
                              void* d_out, int out_size, void* d_ws, size_t ws_size,
                              hipStream_t stream)
{
    const float* X    = (const float*)d_in[0];
    const float* cw   = (const float*)d_in[1];
    const float* cb   = (const float*)d_in[2];
    const float* Wi1  = (const float*)d_in[3];
    const float* Wh1  = (const float*)d_in[4];
    const float* b1   = (const float*)d_in[5];
    const float* Wi2  = (const float*)d_in[6];
    const float* Wh2  = (const float*)d_in[7];
    const float* b2   = (const float*)d_in[8];
    const float* Wi3  = (const float*)d_in[9];
    const float* Wh3  = (const float*)d_in[10];
    const float* b3   = (const float*)d_in[11];
    const float* Wi4  = (const float*)d_in[12];
    const float* Wh4  = (const float*)d_in[13];
    const float* b4   = (const float*)d_in[14];
    const float* attW = (const float*)d_in[15];
    const float* attWb= (const float*)d_in[16];
    const float* attV = (const float*)d_in[17];
    const float* attVb= (const float*)d_in[18];
    const float* d1W  = (const float*)d_in[19];
    const float* d1b  = (const float*)d_in[20];
    const float* d2W  = (const float*)d_in[21];
    const float* d2b  = (const float*)d_in[22];
    float* out = (float*)d_out;

    // workspace layout (total 137,580,544 B ~ 131.2 MiB — under r2's proven 169 MB):
    char* w = (char*)d_ws;
    u16*   x12  = (u16*)w;                          // 33,554,432
    u16*   pre  = (u16*)(w + 33554432);             // 33,554,432 (per chunk, 2 layers)
    u16*   enc  = (u16*)(w + 67108864);             // 67,108,864
    u32*   wpk  = (u32*)(w + 134217728);            //  1,048,576
    float* state= (float*)(w + 135266304);          //    262,144
    u32*   wi3T = (u32*)(w + 135528448);            //    524,288
    u32*   wi4T = (u32*)(w + 136052736);            //    524,288
    u32*   awT  = (u32*)(w + 136577024);            //    131,072
    uint4* wpkT = (uint4*)(w + 136708096);          //    491,520 (2*15*1024*16)
    u32*   whs  = (u32*)(w + 137199616);            //    262,144
    float* w4s  = (float*)(w + 137461760);          //     16,384
    float* beffs= (float*)(w + 137478144);          //      4,096
    float* sstC = (float*)(w + 137482240);          //     65,536
    u16*   sstH = (u16*)(w + 137547776);            //     32,768
    float* S1   = (float*)(w + 33554432);           // 32 MiB, aliases pre (dead after chunks)

    cvt_all<<<2556, 256, 0, stream>>>(Wh3, Wh4, Wi3, Wi4, attW, Wh1, Wh2, cw, cb,
                                      Wi1, Wi2, b1, b2,
                                      wpk, wi3T, wi4T, awT, wpkT, whs, w4s, beffs);

    for (int c = 0; c <= NCH; ++c) {
        fused_step<<<256, 512, 0, stream>>>(pre, wpk, wpkT, state, enc,
                                            X, whs, w4s, beffs, sstC, sstH, x12, c);
        if (c < NCH)
            gemm_mfma<0, 1, 1><<<dim3(128, 8), 256, 0, stream>>>(
                x12, wi3T, wi4T, b3, b4, pre, c * TC_, 1024, 256);
    }

    gemm_mfma<1, 0, 0><<<dim3(512, 1), 256, 0, stream>>>(
        enc, awT, awT, attWb, attWb, S1, 0, 128, 512);
    attn_head<<<64, 256, 0, stream>>>(S1, enc, attV, attVb, d1W, d1b, d2W, d2b, out);
}

// Round 17
// 2111.118 us; speedup vs baseline: 1.6083x; 1.5060x over previous
//
#include <hip/hip_runtime.h>
#include <hip/hip_fp16.h>

// Sizes fixed by the problem.
#define B_   64
#define T_   1024
#define H1_  128
#define H2_  256
#define TC_  128              // time-chunk for LSTM3/4 and LSTM1/2
#define NCH  (T_ / TC_)       // 8 chunks
#define MCH  (B_ * TC_)       // 8192 rows per chunk per layer

typedef unsigned int  u32;
typedef unsigned short u16;
typedef _Float16 half2_t __attribute__((ext_vector_type(2)));
typedef _Float16 half8 __attribute__((ext_vector_type(8)));
typedef float f32x4 __attribute__((ext_vector_type(4)));

__device__ __forceinline__ float fdot2(u32 w, u32 h, float acc) {
    return __builtin_amdgcn_fdot2(__builtin_bit_cast(half2_t, w),
                                  __builtin_bit_cast(half2_t, h), acc, false);
}
__device__ __forceinline__ u32 pk2(float a, float b) {
    __half2 h = __floats2half2_rn(a, b);
    return __builtin_bit_cast(u32, h);
}
__device__ __forceinline__ float hf(u16 u) { return __half2float(__builtin_bit_cast(__half, u)); }
__device__ __forceinline__ u16 fh(float f) { return __builtin_bit_cast(u16, __float2half(f)); }
__device__ __forceinline__ float sigf(float x) { return 1.0f / (1.0f + expf(-x)); }

// ---------------------------------------------------------------------------
// Weight conversions (packed fp16 pairs) + small-LSTM prologue precompute:
//  wpk  [2][128][1024]: Wh3/Wh4 pairs (k2, col j)
//  wi3T [1024][128]:    Wi3 pairs, N-major (for MFMA B staging)
//  wi4T [1024][128]:    Wi4 pairs, N-major, feature-flip baked in
//  awT  [128][256]:     attW pairs, N-major
//  wpkT [2][14][1024]:  Wh3/Wh4 pairs k2=72..127 lane-contiguous uint4 stream
//  whs  [2][64][512]:   Wh1/Wh2 pairs
//  w4s, beffs:          conv-folded taps/bias
// ---------------------------------------------------------------------------
__global__ void cvt_all(const float* __restrict__ Wh3, const float* __restrict__ Wh4,
                        const float* __restrict__ Wi3, const float* __restrict__ Wi4,
                        const float* __restrict__ attW,
                        const float* __restrict__ Wh1, const float* __restrict__ Wh2,
                        const float* __restrict__ cw, const float* __restrict__ cb,
                        const float* __restrict__ Wi1, const float* __restrict__ Wi2,
                        const float* __restrict__ b1, const float* __restrict__ b2,
                        u32* __restrict__ wpk, u32* __restrict__ wi3T,
                        u32* __restrict__ wi4T, u32* __restrict__ awT,
                        uint4* __restrict__ wpkT, u32* __restrict__ whs,
                        float* __restrict__ w4s, float* __restrict__ beffs)
{
    int idx = blockIdx.x * 256 + threadIdx.x;   // < 652288
    if (idx < 262144) {
        int l = idx >> 17, rem = idx & 131071, k2 = rem >> 10, j = rem & 1023;
        const float* W = l ? Wh4 : Wh3;
        wpk[idx] = pk2(W[(2 * k2) * 1024 + j], W[(2 * k2 + 1) * 1024 + j]);
    } else if (idx < 393216) {
        int rel = idx - 262144, n = rel >> 7, kp = rel & 127;   // [n][kp]
        wi3T[rel] = pk2(Wi3[(2 * kp) * 1024 + n], Wi3[(2 * kp + 1) * 1024 + n]);
    } else if (idx < 524288) {
        int rel = idx - 393216, n = rel >> 7, kp = rel & 127;   // [n][kp], flip
        wi4T[rel] = pk2(Wi4[(255 - 2 * kp) * 1024 + n], Wi4[(254 - 2 * kp) * 1024 + n]);
    } else if (idx < 557056) {
        int rel = idx - 524288, n = rel >> 8, kp = rel & 255;   // [n][kp]
        awT[rel] = pk2(attW[(2 * kp) * 128 + n], attW[(2 * kp + 1) * 128 + n]);
    } else if (idx < 585728) {
        int rel = idx - 557056;          // < 28672 = 2 * 14 * 1024
        int l = rel / 14336;
        int rem = rel - l * 14336;
        int q = rem >> 10, col = rem & 1023;
        const float* W = l ? Wh4 : Wh3;
        int k2 = 72 + 4 * q;
        uint4 v;
        v.x = pk2(W[(2 * k2 + 0) * 1024 + col], W[(2 * k2 + 1) * 1024 + col]);
        v.y = pk2(W[(2 * k2 + 2) * 1024 + col], W[(2 * k2 + 3) * 1024 + col]);
        v.z = pk2(W[(2 * k2 + 4) * 1024 + col], W[(2 * k2 + 5) * 1024 + col]);
        v.w = pk2(W[(2 * k2 + 6) * 1024 + col], W[(2 * k2 + 7) * 1024 + col]);
        wpkT[rel] = v;
    } else if (idx < 651264) {
        int rel = idx - 585728;          // < 65536 = 2 * 64 * 512
        int l = rel >> 15, rem = rel & 32767, p = rem >> 9, col = rem & 511;
        const float* W = l ? Wh2 : Wh1;
        whs[rel] = pk2(W[(2 * p) * 512 + col], W[(2 * p + 1) * 512 + col]);
    } else if (idx < 652288) {
        int rel = idx - 651264;          // < 1024
        int l = rel >> 9, col = rel & 511;
        const float* Wi = l ? Wi2 : Wi1;
        const float* bb = l ? b2 : b1;
#pragma unroll
        for (int kk = 0; kk < 4; ++kk) {
            float s = 0.f;
#pragma unroll
            for (int c0 = 0; c0 < 16; ++c0) {
                int cc = l ? (15 - c0) : c0;
                s += cw[kk * 16 + c0] * Wi[cc * 512 + col];
            }
            w4s[(l * 4 + kk) * 512 + col] = s;
        }
        float be = bb[col];
#pragma unroll
        for (int c0 = 0; c0 < 16; ++c0) {
            int cc = l ? (15 - c0) : c0;
            be += cb[c0] * Wi[cc * 512 + col];
        }
        beffs[l * 512 + col] = be;
    }
}

// ---------------------------------------------------------------------------
// FUSED persistent step: 256 blocks, 512 threads. (r13-proven configuration:
// big residency 36 VGPR-pairs + 36 LDS-pairs + 56 L2-streamed pairs per col —
// step is ~85% of the L2-stream floor; AGPR alternatives all slower, r14-r16)
//  blocks   0..127: LSTM3/4 (big) chunk c-1  (skipped when c == 0)
//  blocks 128..255: LSTM1/2 (small) chunk c  (skipped when c == NCH)
// ---------------------------------------------------------------------------
__global__ __launch_bounds__(512) void fused_step(
    const u16* __restrict__ pre, const u32* __restrict__ wpk,
    const uint4* __restrict__ wpkT, float* __restrict__ state,
    u16* __restrict__ enc,
    const float* __restrict__ X, const u32* __restrict__ whs,
    const float* __restrict__ w4s, const float* __restrict__ beffs,
    float* __restrict__ sstC, u16* __restrict__ sstH,
    u16* __restrict__ x12, int c)
{
    __shared__ __align__(16) uint4 wlA[9][512];
    __shared__ __align__(16) uint4 wlB[9][512];
    __shared__ __align__(16) u32 hbuf_pk[128];
    __shared__ float zbuf[1024];
    __shared__ __align__(16) u32 hbs[64];

    const int j = threadIdx.x;

    if (blockIdx.x < 128) {
        // ----------------------------- BIG ---------------------------------
        if (c == 0) return;
        const int t0 = (c - 1) * TC_;
        const int blk = blockIdx.x;
        const int b = blk >> 1;
        const int layer = blk & 1;

        const u32* wp = wpk + (size_t)layer * 131072;
        u32 wrA[36], wrB[36];
#pragma unroll
        for (int q = 0; q < 36; ++q) {
            wrA[q] = wp[q * 1024 + j];
            wrB[q] = wp[q * 1024 + 512 + j];
        }
#pragma unroll
        for (int m = 0; m < 9; ++m) {
            uint4 va, vb;
            va.x = wp[(36 + 4 * m + 0) * 1024 + j];
            va.y = wp[(36 + 4 * m + 1) * 1024 + j];
            va.z = wp[(36 + 4 * m + 2) * 1024 + j];
            va.w = wp[(36 + 4 * m + 3) * 1024 + j];
            vb.x = wp[(36 + 4 * m + 0) * 1024 + 512 + j];
            vb.y = wp[(36 + 4 * m + 1) * 1024 + 512 + j];
            vb.z = wp[(36 + 4 * m + 2) * 1024 + 512 + j];
            vb.w = wp[(36 + 4 * m + 3) * 1024 + 512 + j];
            wlA[m][j] = va;
            wlB[m][j] = vb;
        }
        const uint4* wt = wpkT + (size_t)layer * 14 * 1024;

        float* st = state + ((size_t)layer * B_ + b) * 512;
        u16* hb16 = (u16*)hbuf_pk;
        float c_state = 0.f, h_last = 0.f;
        if (j < 256) {
            float h0 = (t0 == 0) ? 0.f : st[256 + j];
            c_state = (t0 == 0) ? 0.f : st[j];
            hb16[j] = fh(h0);
            h_last = h0;
        }
        __syncthreads();

        const u16* prow = pre + (size_t)(layer * MCH + b * TC_) * 1024;
        u16* encrow = enc + ((size_t)b * T_ + t0) * 512 + layer * 256;
        const uint4* hp4 = (const uint4*)hbuf_pk;

        for (int tt = 0; tt < TC_; ++tt, prow += 1024, encrow += 512) {
            u16 pA = prow[j], pB = prow[512 + j];
            float a0 = 0.f, a1 = 0.f, b0 = 0.f, b1 = 0.f;
#pragma unroll
            for (int m = 0; m < 9; ++m) {           // pairs 0..35 from VGPR
                uint4 hh = hp4[m];
                a0 = fdot2(wrA[4 * m + 0], hh.x, a0);
                a1 = fdot2(wrA[4 * m + 1], hh.y, a1);
                a0 = fdot2(wrA[4 * m + 2], hh.z, a0);
                a1 = fdot2(wrA[4 * m + 3], hh.w, a1);
                b0 = fdot2(wrB[4 * m + 0], hh.x, b0);
                b1 = fdot2(wrB[4 * m + 1], hh.y, b1);
                b0 = fdot2(wrB[4 * m + 2], hh.z, b0);
                b1 = fdot2(wrB[4 * m + 3], hh.w, b1);
            }
#pragma unroll
            for (int m = 0; m < 9; ++m) {           // pairs 36..71 from LDS
                uint4 hh = hp4[9 + m];
                uint4 wa = wlA[m][j];
                uint4 wb = wlB[m][j];
                a0 = fdot2(wa.x, hh.x, a0); a1 = fdot2(wa.y, hh.y, a1);
                a0 = fdot2(wa.z, hh.z, a0); a1 = fdot2(wa.w, hh.w, a1);
                b0 = fdot2(wb.x, hh.x, b0); b1 = fdot2(wb.y, hh.y, b1);
                b0 = fdot2(wb.z, hh.z, b0); b1 = fdot2(wb.w, hh.w, b1);
            }
#pragma unroll
            for (int q = 0; q < 14; ++q) {          // pairs 72..127 streamed (L2)
                uint4 hh = hp4[18 + q];
                uint4 wa = wt[q * 1024 + j];
                uint4 wb = wt[q * 1024 + 512 + j];
                a0 = fdot2(wa.x, hh.x, a0); a1 = fdot2(wa.y, hh.y, a1);
                a0 = fdot2(wa.z, hh.z, a0); a1 = fdot2(wa.w, hh.w, a1);
                b0 = fdot2(wb.x, hh.x, b0); b1 = fdot2(wb.y, hh.y, b1);
                b0 = fdot2(wb.z, hh.z, b0); b1 = fdot2(wb.w, hh.w, b1);
            }
            float zA = (a0 + a1) + hf(pA);          // col j: gate i or f
            float zB = (b0 + b1) + hf(pB);          // col 512+j: gate g or o
            zbuf[j] = sigf(zA);
            zbuf[512 + j] = (j < 256) ? tanhf(zB) : sigf(zB);
            __syncthreads();
            if (j < 256) {
                float gi = zbuf[j], gf = zbuf[256 + j], gg = zbuf[512 + j], go = zbuf[768 + j];
                c_state = gf * c_state + gi * gg;
                float h = go * tanhf(c_state);
                hb16[j] = fh(h);
                encrow[j] = fh(h);
                h_last = h;
            }
            __syncthreads();
        }
        if (j < 256) { st[j] = c_state; st[256 + j] = h_last; }
    } else {
        // ---------------------------- SMALL --------------------------------
        if (c >= NCH) return;
        const int chain = blockIdx.x - 128;
        const int b = chain >> 1;
        const int layer = chain & 1;

        float W4[4];
#pragma unroll
        for (int kk = 0; kk < 4; ++kk) W4[kk] = w4s[(layer * 4 + kk) * 512 + j];
        float beff = beffs[layer * 512 + j];
        u32 whp[64];
#pragma unroll
        for (int p = 0; p < 64; ++p) whp[p] = whs[(layer * 64 + p) * 512 + j];

        u16* hb16 = (u16*)hbs;
        float c_state = 0.f;
        if (j < 128) {
            if (c == 0) hb16[j] = 0;
            else { c_state = sstC[chain * 128 + j]; hb16[j] = sstH[chain * 128 + j]; }
        }
        const int t0 = c * TC_;
        const float* Xb = X + (size_t)b * T_;
        float xm1 = (t0 == 0) ? 0.f : Xb[t0 - 1];
        float x0 = Xb[t0], xp1 = Xb[t0 + 1], xp2 = Xb[t0 + 2];
        __syncthreads();

        const uint4* hp4 = (const uint4*)hbs;
        u16 hprev = 0;
        for (int t = t0; t < t0 + TC_; ++t) {
            float xnext = (t + 3 < T_) ? Xb[t + 3] : 0.f;

            float za = beff + xm1 * W4[0] + x0 * W4[1] + xp1 * W4[2] + xp2 * W4[3];
            float zb = 0.f, zc = 0.f, zd = 0.f;
#pragma unroll
            for (int m = 0; m < 16; ++m) {
                uint4 hh = hp4[m];
                za = fdot2(whp[4 * m + 0], hh.x, za);
                zb = fdot2(whp[4 * m + 1], hh.y, zb);
                zc = fdot2(whp[4 * m + 2], hh.z, zc);
                zd = fdot2(whp[4 * m + 3], hh.w, zd);
            }
            float z = (za + zb) + (zc + zd);
            zbuf[j] = (j >= 256 && j < 384) ? tanhf(z) : sigf(z);
            __syncthreads();
            if (j < 128) {
                float gi = zbuf[j], gf = zbuf[128 + j], gg = zbuf[256 + j], go = zbuf[384 + j];
                c_state = gf * c_state + gi * gg;
                float h = go * tanhf(c_state);
                hprev = fh(h);
                hb16[j] = hprev;
                x12[((size_t)b * T_ + t) * 256 + layer * 128 + j] = hprev;
            }
            xm1 = x0; x0 = xp1; xp1 = xp2; xp2 = xnext;
            __syncthreads();
        }
        if (j < 128) { sstC[chain * 128 + j] = c_state; sstH[chain * 128 + j] = hprev; }
    }
}

// ---------------------------------------------------------------------------
// MFMA fp16 GEMM (r13-verified: bit-identical absmax confirms operand layout)
// ---------------------------------------------------------------------------
template<int OUTMODE, int CHUNK, int LAYERED>
__global__ __launch_bounds__(256) void gemm_mfma(
    const u16* __restrict__ A, const u32* __restrict__ B0, const u32* __restrict__ B1,
    const float* __restrict__ bias0, const float* __restrict__ bias1,
    void* __restrict__ outv, int t0, int N, int K)
{
    __shared__ __align__(16) u32 Al[128][20];   // [row][16 u32 k + 4 pad]
    __shared__ __align__(16) u32 Bl[128][20];   // [col][16 u32 k + 4 pad]
    const int tid = threadIdx.x;
    const int bx = blockIdx.x;
    const int layer = LAYERED ? (bx >> 6) : 0;
    const int m0 = LAYERED ? ((bx & 63) * 128) : (bx * 128);
    const int n0 = blockIdx.y * 128;
    const u32* Bpk = layer ? B1 : B0;
    const float* bias = layer ? bias1 : bias0;
    const int K2 = K >> 1;

    const int w = tid >> 6;
    const int lane = tid & 63;
    const int wr = (w >> 1) * 64, wc = (w & 1) * 64;
    const int lr = lane & 15, lg = lane >> 4;

    f32x4 acc[4][4];
#pragma unroll
    for (int r = 0; r < 4; ++r)
#pragma unroll
        for (int c = 0; c < 4; ++c) acc[r][c] = (f32x4){0.f, 0.f, 0.f, 0.f};

    for (int k0 = 0; k0 < K; k0 += 32) {
        const int kp0 = k0 >> 1;
#pragma unroll
        for (int it = 0; it < 2; ++it) {
            int idx = tid + it * 256;
            int row = idx >> 2, q = idx & 3;
            int grow = m0 + row;
            size_t garow = CHUNK ? ((size_t)(grow >> 7) * T_ + t0 + (grow & 127)) : (size_t)grow;
            uint4 ua = *(const uint4*)(A + garow * K + k0 + q * 8);
            *(uint4*)&Al[row][q * 4] = ua;
            uint4 ub = *(const uint4*)(Bpk + (size_t)(n0 + row) * K2 + kp0 + q * 4);
            *(uint4*)&Bl[row][q * 4] = ub;
        }
        __syncthreads();
        half8 bfr[4];
#pragma unroll
        for (int c = 0; c < 4; ++c) {
            const u32* bp = &Bl[wc + c * 16 + lr][0];
            uint2 blo = *(const uint2*)(bp + 2 * lg);
            uint2 bhi = *(const uint2*)(bp + 8 + 2 * lg);
            uint4 bf = make_uint4(blo.x, blo.y, bhi.x, bhi.y);
            bfr[c] = __builtin_bit_cast(half8, bf);
        }
#pragma unroll
        for (int r = 0; r < 4; ++r) {
            const u32* ap = &Al[wr + r * 16 + lr][0];
            uint2 alo = *(const uint2*)(ap + 2 * lg);
            uint2 ahi = *(const uint2*)(ap + 8 + 2 * lg);
            uint4 af = make_uint4(alo.x, alo.y, ahi.x, ahi.y);
            half8 av = __builtin_bit_cast(half8, af);
#pragma unroll
            for (int c = 0; c < 4; ++c)
                acc[r][c] = __builtin_amdgcn_mfma_f32_16x16x32_f16(av, bfr[c], acc[r][c], 0, 0, 0);
        }
        __syncthreads();
    }

    if (OUTMODE == 0) {
        u16* outp = (u16*)outv + (LAYERED ? (size_t)layer * MCH * 1024 : 0);
#pragma unroll
        for (int c = 0; c < 4; ++c) {
            int col = n0 + wc + c * 16 + lr;
            float bvs = bias[col];
#pragma unroll
            for (int r = 0; r < 4; ++r) {
                int orow = m0 + wr + r * 16 + 4 * lg;
#pragma unroll
                for (int i = 0; i < 4; ++i)
                    outp[(size_t)(orow + i) * N + col] = fh(acc[r][c][i] + bvs);
            }
        }
    } else {
        float* outp = (float*)outv;
#pragma unroll
        for (int c = 0; c < 4; ++c) {
            int col = n0 + wc + c * 16 + lr;
            float bvs = bias[col];
#pragma unroll
            for (int r = 0; r < 4; ++r) {
                int orow = m0 + wr + r * 16 + 4 * lg;
#pragma unroll
                for (int i = 0; i < 4; ++i)
                    outp[(size_t)(orow + i) * N + col] = tanhf(acc[r][c][i] + bvs);
            }
        }
    }
}

// ---------------------------------------------------------------------------
// Attention pooling + head, one workgroup per batch. (unchanged)
// ---------------------------------------------------------------------------
__global__ __launch_bounds__(256) void attn_head(
    const float* __restrict__ S1, const u16* __restrict__ enc,
    const float* __restrict__ attV, const float* __restrict__ attVb,
    const float* __restrict__ d1W, const float* __restrict__ d1b,
    const float* __restrict__ d2W, const float* __restrict__ d2b,
    float* __restrict__ out)
{
    const int b = blockIdx.x;
    const int tid = threadIdx.x;
    const int lane = tid & 63, w = tid >> 6;

    __shared__ float sb[1024];
    __shared__ float red[32];
    __shared__ __align__(16) float ctx[512];
    __shared__ float h1s[128];

    float av0 = attV[lane], av1 = attV[64 + lane];
    const float* S1b = S1 + (size_t)b * T_ * 128;
    for (int it = 0; it < 256; ++it) {
        int t = it * 4 + w;
        const float* row = S1b + (size_t)t * 128;
        float p = row[lane] * av0 + row[64 + lane] * av1;
#pragma unroll
        for (int off = 32; off > 0; off >>= 1) p += __shfl_down(p, off);
        if (lane == 0) sb[t] = p + attVb[0];
    }
    __syncthreads();

    float mx = -3.0e38f;
#pragma unroll
    for (int q = 0; q < 4; ++q) mx = fmaxf(mx, sb[tid + 256 * q]);
#pragma unroll
    for (int off = 32; off > 0; off >>= 1) mx = fmaxf(mx, __shfl_down(mx, off));
    if (lane == 0) red[w] = mx;
    __syncthreads();
    if (tid == 0) red[8] = fmaxf(fmaxf(red[0], red[1]), fmaxf(red[2], red[3]));
    __syncthreads();
    float bm = red[8];
    float s = 0.f;
#pragma unroll
    for (int q = 0; q < 4; ++q) {
        float e = expf(sb[tid + 256 * q] - bm);
        sb[tid + 256 * q] = e;
        s += e;
    }
#pragma unroll
    for (int off = 32; off > 0; off >>= 1) s += __shfl_down(s, off);
    if (lane == 0) red[16 + w] = s;
    __syncthreads();
    if (tid == 0) red[24] = 1.0f / (red[16] + red[17] + red[18] + red[19]);
    __syncthreads();
    float inv = red[24];
#pragma unroll
    for (int q = 0; q < 4; ++q) sb[tid + 256 * q] *= inv;
    __syncthreads();

    const u16* encb = enc + (size_t)b * T_ * 512;
    float a0 = 0.f, a1 = 0.f;
    for (int t = 0; t < T_; ++t) {
        float wt = sb[t];
        a0 += wt * hf(encb[(size_t)t * 512 + tid]);
        a1 += wt * hf(encb[(size_t)t * 512 + 256 + tid]);
    }
    ctx[tid] = a0;
    ctx[256 + tid] = a1;
    __syncthreads();

    if (tid < 128) {
        float s1 = d1b[tid];
        for (int k = 0; k < 512; ++k) s1 += ctx[k] * d1W[k * 128 + tid];
        h1s[tid] = tanhf(s1);
    }
    __syncthreads();
    if (tid < 128) {
        float p = h1s[tid] * d2W[tid];
#pragma unroll
        for (int off = 32; off > 0; off >>= 1) p += __shfl_down(p, off);
        if ((tid & 63) == 0) red[28 + (tid >> 6)] = p;
    }
    __syncthreads();
    if (tid == 0) out[b] = red[28] + red[29] + d2b[0];
}

// ---------------------------------------------------------------------------
extern "C" void kernel_launch(void* const* d_in, const int* in_sizes, int n_in,
                              void* d_out, int out_size, void* d_ws, size_t ws_size,
                              hipStream_t stream)
{
    const float* X    = (const float*)d_in[0];
    const float* cw   = (const float*)d_in[1];
    const float* cb   = (const float*)d_in[2];
    const float* Wi1  = (const float*)d_in[3];
    const float* Wh1  = (const float*)d_in[4];
    const float* b1   = (const float*)d_in[5];
    const float* Wi2  = (const float*)d_in[6];
    const float* Wh2  = (const float*)d_in[7];
    const float* b2   = (const float*)d_in[8];
    const float* Wi3  = (const float*)d_in[9];
    const float* Wh3  = (const float*)d_in[10];
    const float* b3   = (const float*)d_in[11];
    const float* Wi4  = (const float*)d_in[12];
    const float* Wh4  = (const float*)d_in[13];
    const float* b4   = (const float*)d_in[14];
    const float* attW = (const float*)d_in[15];
    const float* attWb= (const float*)d_in[16];
    const float* attV = (const float*)d_in[17];
    const float* attVb= (const float*)d_in[18];
    const float* d1W  = (const float*)d_in[19];
    const float* d1b  = (const float*)d_in[20];
    const float* d2W  = (const float*)d_in[21];
    const float* d2b  = (const float*)d_in[22];
    float* out = (float*)d_out;

    // workspace layout (total 137,547,776 B ~ 131.2 MiB — under r2's proven 169 MB):
    char* w = (char*)d_ws;
    u16*   x12  = (u16*)w;                          // 33,554,432
    u16*   pre  = (u16*)(w + 33554432);             // 33,554,432 (per chunk, 2 layers)
    u16*   enc  = (u16*)(w + 67108864);             // 67,108,864
    u32*   wpk  = (u32*)(w + 134217728);            //  1,048,576
    float* state= (float*)(w + 135266304);          //    262,144
    u32*   wi3T = (u32*)(w + 135528448);            //    524,288
    u32*   wi4T = (u32*)(w + 136052736);            //    524,288
    u32*   awT  = (u32*)(w + 136577024);            //    131,072
    uint4* wpkT = (uint4*)(w + 136708096);          //    458,752
    u32*   whs  = (u32*)(w + 137166848);            //    262,144
    float* w4s  = (float*)(w + 137428992);          //     16,384
    float* beffs= (float*)(w + 137445376);          //      4,096
    float* sstC = (float*)(w + 137449472);          //     65,536
    u16*   sstH = (u16*)(w + 137515008);            //     32,768
    float* S1   = (float*)(w + 33554432);           // 32 MiB, aliases pre (dead after chunks)

    cvt_all<<<2548, 256, 0, stream>>>(Wh3, Wh4, Wi3, Wi4, attW, Wh1, Wh2, cw, cb,
                                      Wi1, Wi2, b1, b2,
                                      wpk, wi3T, wi4T, awT, wpkT, whs, w4s, beffs);

    for (int c = 0; c <= NCH; ++c) {
        fused_step<<<256, 512, 0, stream>>>(pre, wpk, wpkT, state, enc,
                                            X, whs, w4s, beffs, sstC, sstH, x12, c);
        if (c < NCH)
            gemm_mfma<0, 1, 1><<<dim3(128, 8), 256, 0, stream>>>(
                x12, wi3T, wi4T, b3, b4, pre, c * TC_, 1024, 256);
    }

    gemm_mfma<1, 0, 0><<<dim3(512, 1), 256, 0, stream>>>(
        enc, awT, awT, attWb, attWb, S1, 0, 128, 512);
    attn_head<<<64, 256, 0, stream>>>(S1, enc, attV, attVb, d1W, d1b, d2W, d2b, out);
}